// Round 2
// 231.611 us; speedup vs baseline: 1.0538x; 1.0538x over previous
//
#include <hip/hip_runtime.h>

#define WDIM 192
#define PLANE (192 * 192)
#define VOL (192 * 192 * 192)
#define HC 24          // h-rows produced per block in wh_pass
#define TR (HC + 8)    // tile rows incl. halo = 32
#define RWU 100        // uints per padded LDS row: 200 f16 = [2 pad][96 data][2 pad] pairs
#define DC 24          // d-slices per block in d_pass

typedef __fp16 h2f __attribute__((ext_vector_type(2)));

__global__ void zero_out_k(float* out) { out[0] = 0.0f; }

// pack two floats -> one uint holding 2 f16 (RTZ), lo = a, hi = b
static __device__ inline unsigned int pk_h16(float a, float b) {
    h2f v = __builtin_amdgcn_cvt_pkrtz(a, b);
    return __builtin_bit_cast(unsigned int, v);
}
static __device__ inline float h_lo(unsigned int u) {
    h2f v = __builtin_bit_cast(h2f, u); return (float)v.x;
}
static __device__ inline float h_hi(unsigned int u) {
    h2f v = __builtin_bit_cast(h2f, u); return (float)v.y;
}
// f32 += dot(f16pair, f16pair)
static __device__ inline float dot2u(unsigned int a, unsigned int b, float c) {
    return __builtin_amdgcn_fdot2(__builtin_bit_cast(h2f, a),
                                  __builtin_bit_cast(h2f, b), c, false);
}

// --- Pass 1: fused W-box + H-box sums -> 12-byte records (5 f16 sums) ------
// grid (1536, nb): x = d*8 + h_chunk, y = batch.
// LDS: I and J rows staged as f16 PAIRS along w; 9-wide window sums computed
// with v_dot2_f32_f16 (5 pair-dots per sum, parity-masked edges).
__global__ __launch_bounds__(192) void wh_pass(const float* __restrict__ I,
                                               const float* __restrict__ J,
                                               unsigned int* __restrict__ B) {
    __shared__ unsigned int sI[TR * RWU];   // 12800 B
    __shared__ unsigned int sJ[TR * RWU];   // 12800 B
    const int t = threadIdx.x;           // w
    const int d = blockIdx.x >> 3;
    const int c = blockIdx.x & 7;
    const int h0 = c * HC;

    const size_t bofs = (size_t)blockIdx.y * VOL;
    const float* Ib = I + bofs;
    const float* Jb = J + bofs;
    unsigned int* Bb = B + bofs * 3;

    const size_t dbase = (size_t)d * PLANE;

    // zero the 4 pad pair-slots of each row in both arrays (32 rows * 8)
    for (int n = t; n < 256; n += 192) {
        const int row = n >> 3;
        const int p = n & 7;
        unsigned int* dst = (p < 4) ? sI : sJ;
        const int q = p & 3;
        const int col = (q < 2) ? q : (96 + q);   // {0,1,98,99}
        dst[row * RWU + col] = 0u;
    }

    // cooperative staging: rows 0..31, data pairs at uint index 2 + w/2
    #pragma unroll
    for (int i = 0; i < 8; ++i) {
        const int idx4 = i * 192 + t;        // 0..1535
        const int row  = idx4 / 48;          // 0..31
        const int col4 = (idx4 - row * 48) * 4;
        const int h = h0 - 4 + row;
        float4 vI = make_float4(0.f, 0.f, 0.f, 0.f);
        float4 vJ = vI;
        if (h >= 0 && h < WDIM) {
            vI = *(const float4*)(Ib + dbase + (size_t)h * WDIM + col4);
            vJ = *(const float4*)(Jb + dbase + (size_t)h * WDIM + col4);
        }
        uint2 uI, uJ;
        uI.x = pk_h16(vI.x, vI.y); uI.y = pk_h16(vI.z, vI.w);
        uJ.x = pk_h16(vJ.x, vJ.y); uJ.y = pk_h16(vJ.z, vJ.w);
        const int ui = row * RWU + 2 + (col4 >> 1);   // even -> 8B aligned
        *(uint2*)&sI[ui] = uI;
        *(uint2*)&sJ[ui] = uJ;
    }
    __syncthreads();

    // window for output w=t covers f16 elements E=t..t+8 -> pairs tb..tb+4
    // even t: exclude hi of pair 4; odd t: exclude lo of pair 0.
    const int tb = t >> 1;
    const int odd = t & 1;
    const unsigned int ONESF = 0x3C003C00u;                       // (1,1) f16
    const unsigned int ones0 = odd ? 0x3C000000u : ONESF;         // edge ones
    const unsigned int ones4 = odd ? ONESF : 0x00003C00u;
    const unsigned int keep0 = odd ? 0xFFFF0000u : 0xFFFFFFFFu;   // operand masks
    const unsigned int keep4 = odd ? 0xFFFFFFFFu : 0x0000FFFFu;

    float ring0[9], ring1[9], ring2[9], ring3[9], ring4[9];
    #pragma unroll
    for (int j = 0; j < 9; ++j) { ring0[j]=0.f; ring1[j]=0.f; ring2[j]=0.f; ring3[j]=0.f; ring4[j]=0.f; }
    float s0 = 0.f, s1 = 0.f, s2 = 0.f, s3 = 0.f, s4 = 0.f;

    unsigned int AI[5], AJ[5], BI[5], BJ[5];
    #pragma unroll
    for (int p = 0; p < 5; ++p) { AI[p] = sI[tb + p]; AJ[p] = sJ[tb + p]; }

    #pragma unroll
    for (int s = 0; s < TR; ++s) {
        if (s + 1 < TR) {
            const int base = (s + 1) * RWU + tb;
            if ((s & 1) == 0) {
                #pragma unroll
                for (int p = 0; p < 5; ++p) { BI[p] = sI[base + p]; BJ[p] = sJ[base + p]; }
            } else {
                #pragma unroll
                for (int p = 0; p < 5; ++p) { AI[p] = sI[base + p]; AJ[p] = sJ[base + p]; }
            }
        }
        const unsigned int c0 = ((s & 1) == 0) ? AI[0] : BI[0];
        const unsigned int c1 = ((s & 1) == 0) ? AI[1] : BI[1];
        const unsigned int c2 = ((s & 1) == 0) ? AI[2] : BI[2];
        const unsigned int c3 = ((s & 1) == 0) ? AI[3] : BI[3];
        const unsigned int c4 = ((s & 1) == 0) ? AI[4] : BI[4];
        const unsigned int e0 = ((s & 1) == 0) ? AJ[0] : BJ[0];
        const unsigned int e1 = ((s & 1) == 0) ? AJ[1] : BJ[1];
        const unsigned int e2 = ((s & 1) == 0) ? AJ[2] : BJ[2];
        const unsigned int e3 = ((s & 1) == 0) ? AJ[3] : BJ[3];
        const unsigned int e4 = ((s & 1) == 0) ? AJ[4] : BJ[4];

        const unsigned int mI0 = c0 & keep0, mI4 = c4 & keep4;
        const unsigned int mJ0 = e0 & keep0, mJ4 = e4 & keep4;

        float w0 = dot2u(c0, ones0, 0.f);
        w0 = dot2u(c1, ONESF, w0); w0 = dot2u(c2, ONESF, w0);
        w0 = dot2u(c3, ONESF, w0); w0 = dot2u(c4, ones4, w0);

        float w1 = dot2u(e0, ones0, 0.f);
        w1 = dot2u(e1, ONESF, w1); w1 = dot2u(e2, ONESF, w1);
        w1 = dot2u(e3, ONESF, w1); w1 = dot2u(e4, ones4, w1);

        float w2 = dot2u(mI0, c0, 0.f);
        w2 = dot2u(c1, c1, w2); w2 = dot2u(c2, c2, w2);
        w2 = dot2u(c3, c3, w2); w2 = dot2u(mI4, c4, w2);

        float w3 = dot2u(mJ0, e0, 0.f);
        w3 = dot2u(e1, e1, w3); w3 = dot2u(e2, e2, w3);
        w3 = dot2u(e3, e3, w3); w3 = dot2u(mJ4, e4, w3);

        float w4 = dot2u(mI0, e0, 0.f);
        w4 = dot2u(c1, e1, w4); w4 = dot2u(c2, e2, w4);
        w4 = dot2u(c3, e3, w4); w4 = dot2u(mI4, e4, w4);

        const int j = s % 9;
        s0 += w0 - ring0[j]; ring0[j] = w0;
        s1 += w1 - ring1[j]; ring1[j] = w1;
        s2 += w2 - ring2[j]; ring2[j] = w2;
        s3 += w3 - ring3[j]; ring3[j] = w3;
        s4 += w4 - ring4[j]; ring4[j] = w4;

        if (s >= 8) {
            const int h_out = h0 + s - 8;
            const size_t idx = dbase + (size_t)h_out * WDIM + t;
            uint3 q;
            q.x = pk_h16(s0, s1);
            q.y = pk_h16(s2, s3);
            q.z = pk_h16(s4, 0.f);
            *(uint3*)(Bb + idx * 3) = q;
        }
    }
}

// --- Pass 2: D-axis sliding box sum + NCC + reduction ----------------------
// 12-byte f16 records; centers re-read from fp32 I,J (L3-served).
__global__ __launch_bounds__(192) void d_pass(const unsigned int* __restrict__ B,
                                              const float* __restrict__ I,
                                              const float* __restrict__ J,
                                              float* __restrict__ out) {
    const int t = threadIdx.x;
    const int h = blockIdx.x >> 3;
    const int c = blockIdx.x & 7;
    const int d0 = c * DC;
    const int base_h = h * WDIM + t;

    const size_t bofs = (size_t)blockIdx.y * VOL;
    const float* Ib = I + bofs;
    const float* Jb = J + bofs;
    const unsigned int* Bb = B + bofs * 3;

    float r0[9], r1[9], r2[9], r3[9], r4[9];
    #pragma unroll
    for (int j = 0; j < 9; ++j) { r0[j]=0.f; r1[j]=0.f; r2[j]=0.f; r3[j]=0.f; r4[j]=0.f; }
    float s0 = 0.f, s1 = 0.f, s2 = 0.f, s3 = 0.f, s4 = 0.f;

    const float inv_k = 1.0f / 729.0f;
    float local = 0.f;

    uint3 qA[8], qB[8];
    float2 cA[8], cB[8];
    // preload group 0 records (steps 0..7, d_in = d0-4 .. d0+3); no outputs yet
    #pragma unroll
    for (int i = 0; i < 8; ++i) {
        const int d_in = d0 - 4 + i;
        qA[i] = make_uint3(0u, 0u, 0u);
        if (d_in >= 0 && d_in < WDIM)
            qA[i] = *(const uint3*)(Bb + ((size_t)d_in * PLANE + base_h) * 3);
        cA[i] = make_float2(0.f, 0.f);
    }

    #pragma unroll
    for (int g = 0; g < 4; ++g) {
        // prefetch group g+1: records + centers
        if (g + 1 < 4) {
            #pragma unroll
            for (int i = 0; i < 8; ++i) {
                const int s = (g + 1) * 8 + i;
                const int d_in = d0 - 4 + s;
                uint3 v = make_uint3(0u, 0u, 0u);
                if (d_in >= 0 && d_in < WDIM)
                    v = *(const uint3*)(Bb + ((size_t)d_in * PLANE + base_h) * 3);
                const int d_out = d0 + s - 8;              // always in [0,192)
                const size_t cidx = (size_t)d_out * PLANE + base_h;
                const float ci = Ib[cidx];
                const float cj = Jb[cidx];
                if ((g & 1) == 0) { qB[i] = v; cB[i] = make_float2(ci, cj); }
                else              { qA[i] = v; cA[i] = make_float2(ci, cj); }
            }
        }
        // process group g
        #pragma unroll
        for (int i = 0; i < 8; ++i) {
            const int s = g * 8 + i;
            const uint3 q = ((g & 1) == 0) ? qA[i] : qB[i];
            const float f0 = h_lo(q.x), f1 = h_hi(q.x);
            const float f2 = h_lo(q.y), f3 = h_hi(q.y);
            const float f4 = h_lo(q.z);
            const int j = s % 9;
            s0 += f0 - r0[j]; r0[j] = f0;
            s1 += f1 - r1[j]; r1[j] = f1;
            s2 += f2 - r2[j]; r2[j] = f2;
            s3 += f3 - r3[j]; r3[j] = f3;
            s4 += f4 - r4[j]; r4[j] = f4;

            if (s >= 8) {
                const float2 cc = ((g & 1) == 0) ? cA[i] : cB[i];
                const float Iu = cc.x * inv_k;
                const float Ju = cc.y * inv_k;
                const float cross = s4 - s0 * Ju - s1 * Iu + Iu * Ju * 729.0f;
                const float Ivar  = s2 - 2.0f * s0 * Iu + Iu * Iu * 729.0f;
                const float Jvar  = s3 - 2.0f * s1 * Ju + Ju * Ju * 729.0f;
                local += (cross * cross) / (Ivar * Jvar + 1e-5f);
            }
        }
    }

    __shared__ float sred[192];
    sred[t] = local;
    __syncthreads();
    if (t < 64) {
        float v = sred[t] + sred[t + 64] + sred[t + 128];
        #pragma unroll
        for (int off = 32; off; off >>= 1) v += __shfl_down(v, off);
        if (t == 0) {
            atomicAdd(out, v * (-1.0f / 14155776.0f));
        }
    }
}

extern "C" void kernel_launch(void* const* d_in, const int* in_sizes, int n_in,
                              void* d_out, int out_size, void* d_ws, size_t ws_size,
                              hipStream_t stream) {
    const float* I = (const float*)d_in[0];
    const float* J = (const float*)d_in[1];
    float* out = (float*)d_out;
    unsigned int* B = (unsigned int*)d_ws;

    zero_out_k<<<1, 1, 0, stream>>>(out);

    const size_t need2 = (size_t)2 * VOL * 12;   // 169.9 MB for both batches
    if (ws_size >= need2) {
        // merged path: both batches in one launch pair
        wh_pass<<<dim3(1536, 2), 192, 0, stream>>>(I, J, B);
        d_pass <<<dim3(1536, 2), 192, 0, stream>>>(B, I, J, out);
    } else {
        // serial fallback: one 85 MB B volume, per-batch
        for (int b = 0; b < 2; ++b) {
            const float* Ib = I + (size_t)b * VOL;
            const float* Jb = J + (size_t)b * VOL;
            wh_pass<<<dim3(1536, 1), 192, 0, stream>>>(Ib, Jb, B);
            d_pass <<<dim3(1536, 1), 192, 0, stream>>>(B, Ib, Jb, out);
        }
    }
}